// Round 1
// 1207.921 us; speedup vs baseline: 1.0336x; 1.0336x over previous
//
#include <hip/hip_runtime.h>
#include <cstdint>
#include <cstddef>

// ---- problem constants ----
constexpr int G = 8;            // groups
constexpr int S = 1024;         // tokens per group
constexpr int E = 8;            // experts
constexpr int MD = 1024;        // model dim
constexpr int H = 5464;         // ffn dim
constexpr int HP = 5504;        // ffn dim padded to 43*128
constexpr int N1 = 2 * HP;      // 11008: w0/w1 column-interleaved (128-row granules)
constexpr int CAP = 256;        // capacity per (group, expert)
constexpr int T = G * S;        // 8192 tokens
constexpr int GC = G * CAP;     // 2048 rows per expert
constexpr int BK = 64;          // K-step of the 256x256 GEMM tiles

typedef __bf16 bf16;
typedef __bf16 bf16x8 __attribute__((ext_vector_type(8)));
typedef __bf16 bf16x4 __attribute__((ext_vector_type(4)));
typedef float f32x4 __attribute__((ext_vector_type(4)));

__device__ __forceinline__ void async16(const void* g, void* l) {
    // global -> LDS direct DMA, 16B per lane; LDS dst = wave-uniform base + lane*16
    __builtin_amdgcn_global_load_lds((__attribute__((address_space(1))) void*)(g),
                                     (__attribute__((address_space(3))) void*)(l),
                                     16, 0, 0);
}

__device__ __forceinline__ float gelu_tanh(float x) {
    return 0.5f * x * (1.0f + tanhf(0.7978845608028654f * (x + 0.044715f * x * x * x)));
}

// swizzled element offset inside a [rows][64 k] bf16 LDS tile.
// granule = 8 bf16 (16B). LDS granule (row*8 + s) holds global k-granule (s ^ (row&7)).
__device__ __forceinline__ int sw_elem(int row, int gi) {
    return (row * 8 + (gi ^ (row & 7))) * 8;
}

#define BARRIER()   __builtin_amdgcn_s_barrier()
#define FENCE()     asm volatile("" ::: "memory")
#define WAITV(n)    asm volatile("s_waitcnt vmcnt(" #n ")" ::: "memory")
#define WAITLGKM0() asm volatile("s_waitcnt lgkmcnt(0)" ::: "memory")

// ---------------- router: logits + softmax + top2 (fp32, exact semantics) ----------------
__global__ void router_k(const float* __restrict__ x, const float* __restrict__ rw,
                         int* __restrict__ idx1, int* __restrict__ idx2,
                         float* __restrict__ gate1, float* __restrict__ gate2) {
    int wave = threadIdx.x >> 6, lane = threadIdx.x & 63;
    int t = blockIdx.x * 4 + wave;
    const float* xr = x + (size_t)t * MD;
    float acc[E];
#pragma unroll
    for (int e = 0; e < E; e++) acc[e] = 0.0f;
    for (int m = lane; m < MD; m += 64) {
        float xv = xr[m];
        const float* w = rw + m * E;
#pragma unroll
        for (int e = 0; e < E; e++) acc[e] += xv * w[e];
    }
#pragma unroll
    for (int off = 32; off > 0; off >>= 1) {
#pragma unroll
        for (int e = 0; e < E; e++) acc[e] += __shfl_xor(acc[e], off, 64);
    }
    if (lane == 0) {
        float mx = acc[0];
#pragma unroll
        for (int e = 1; e < E; e++) mx = fmaxf(mx, acc[e]);
        float raw[E]; float sum = 0.0f;
#pragma unroll
        for (int e = 0; e < E; e++) { raw[e] = expf(acc[e] - mx); sum += raw[e]; }
        float inv = 1.0f / sum;
#pragma unroll
        for (int e = 0; e < E; e++) raw[e] *= inv;
        int i1 = 0; float b1 = raw[0];
#pragma unroll
        for (int e = 1; e < E; e++) if (raw[e] > b1) { b1 = raw[e]; i1 = e; }
        int i2 = 0; float b2 = -1.0f;
#pragma unroll
        for (int e = 0; e < E; e++) {
            float v = (e == i1) ? 0.0f : raw[e];
            if (v > b2) { b2 = v; i2 = e; }
        }
        idx1[t] = i1; idx2[t] = i2; gate1[t] = b1; gate2[t] = b2;
    }
}

// ---------------- capacity scan: one wave per group, ballot prefix ----------------
__global__ void scan_k(const int* __restrict__ idx1, const int* __restrict__ idx2,
                       const float* __restrict__ gate1, const float* __restrict__ gate2,
                       int* __restrict__ tok1, int* __restrict__ tok2,
                       float* __restrict__ g1m, float* __restrict__ g2m,
                       int* __restrict__ slot_src, int* __restrict__ fill) {
    int g = blockIdx.x;
    int lane = threadIdx.x;
    unsigned long long lt = (1ull << lane) - 1ull;
    int cnt1[E], cnt2[E];
#pragma unroll
    for (int e = 0; e < E; e++) { cnt1[e] = 0; cnt2[e] = 0; }
    for (int ch = 0; ch < S / 64; ch++) {
        int s = ch * 64 + lane, t = g * S + s;
        int i1 = idx1[t];
        int p = 0;
#pragma unroll
        for (int e = 0; e < E; e++) {
            unsigned long long m = __ballot(i1 == e);
            if (i1 == e) p = cnt1[e] + (int)__popcll(m & lt);
            cnt1[e] += (int)__popcll(m);
        }
        bool kept = p < CAP;
        tok1[t] = kept ? (i1 * CAP + p) : -1;
        g1m[t] = kept ? gate1[t] : 0.0f;
        if (kept) slot_src[((i1 * G + g) << 8) + p] = s;
    }
    int m1c[E];
#pragma unroll
    for (int e = 0; e < E; e++) m1c[e] = min(cnt1[e], CAP);
    for (int ch = 0; ch < S / 64; ch++) {
        int s = ch * 64 + lane, t = g * S + s;
        int i2 = idx2[t];
        float g2 = gate2[t];
        int p = 0;
#pragma unroll
        for (int e = 0; e < E; e++) {
            unsigned long long m = __ballot(i2 == e);
            if (i2 == e) p = m1c[e] + cnt2[e] + (int)__popcll(m & lt);
            cnt2[e] += (int)__popcll(m);
        }
        bool kept = p < CAP;
        bool nz = (g2 != 0.0f);
        tok2[t] = (kept && nz) ? (i2 * CAP + p) : -1;
        g2m[t] = (kept && nz) ? g2 : 0.0f;
        if (kept) slot_src[((i2 * G + g) << 8) + p] = nz ? s : -1;
    }
    if (lane < E) fill[lane * G + g] = min(m1c[lane] + cnt2[lane], CAP);
}

// ---------------- gather tokens into expert_in (bf16), zero unfilled slots ----------------
__global__ void gather_k(const float* __restrict__ x, const int* __restrict__ slot_src,
                         const int* __restrict__ fill, bf16* __restrict__ ein) {
    int slot = blockIdx.x;                       // (e*G+g)*CAP + c
    int c = slot & 255, g = (slot >> 8) & 7, e = slot >> 11;
    int i = threadIdx.x * 4;
    int src = (c < fill[e * G + g]) ? slot_src[slot] : -1;
    bf16x4 v;
    if (src >= 0) {
        float4 f = *(const float4*)(x + ((size_t)(g * S + src)) * MD + i);
        v[0] = (bf16)f.x; v[1] = (bf16)f.y; v[2] = (bf16)f.z; v[3] = (bf16)f.w;
    } else {
        v[0] = (bf16)0.0f; v[1] = (bf16)0.0f; v[2] = (bf16)0.0f; v[3] = (bf16)0.0f;
    }
    *(bf16x4*)(ein + (size_t)slot * MD + i) = v;
}

// ---------------- fp32 -> bf16 transpose with zero pad (+optional w0/w1 interleave) ----------------
// in:  (R x Cc) fp32 row-major, batch stride R*Cc
// out: (Cp x Rp) bf16 row-major, batch stride Cp*Rp; out[c][r] = (c<Cc && r<R) ? in[r][c] : 0
// ilv >= 0: output row remapped to ((c>>7)<<8) + ilv + (c&127)  (128-row w0/w1 interleave)
__global__ void transpose_cast_k(const float* __restrict__ in, bf16* __restrict__ out,
                                 int R, int Cc, int Rp, int Cp, int ilv) {
    __shared__ float lds[64][65];
    int c0 = blockIdx.x * 64;
    int r0 = blockIdx.y * 64;
    const float* bin = in + (size_t)blockIdx.z * R * Cc;
    bf16* bout = out + (size_t)blockIdx.z * Cp * Rp;
    int tid = threadIdx.x;
    int lr = tid >> 4;
    int lc = (tid & 15) * 4;
#pragma unroll
    for (int i = 0; i < 4; i++) {
        int r = r0 + lr + i * 16;
        float v0 = 0, v1 = 0, v2 = 0, v3 = 0;
        if (r < R) {
            const float* p = bin + (size_t)r * Cc + c0 + lc;
            if (c0 + lc + 3 < Cc) {
                float4 f = *(const float4*)p;
                v0 = f.x; v1 = f.y; v2 = f.z; v3 = f.w;
            } else {
                if (c0 + lc + 0 < Cc) v0 = p[0];
                if (c0 + lc + 1 < Cc) v1 = p[1];
                if (c0 + lc + 2 < Cc) v2 = p[2];
                if (c0 + lc + 3 < Cc) v3 = p[3];
            }
        }
        lds[lr + i * 16][lc + 0] = v0;
        lds[lr + i * 16][lc + 1] = v1;
        lds[lr + i * 16][lc + 2] = v2;
        lds[lr + i * 16][lc + 3] = v3;
    }
    __syncthreads();
    int orr = tid >> 2;            // out-row offset 0..63
    int oc = (tid & 3) * 16;       // out-col offset 0,16,32,48
    bf16x8 o0, o1;
#pragma unroll
    for (int j = 0; j < 8; j++) o0[j] = (bf16)lds[oc + j][orr];
#pragma unroll
    for (int j = 0; j < 8; j++) o1[j] = (bf16)lds[oc + 8 + j][orr];
    int cc = c0 + orr;
    int r01 = (ilv >= 0) ? (((cc >> 7) << 8) + ilv + (cc & 127)) : cc;
    bf16* dst = bout + (size_t)r01 * Rp + r0 + oc;
    *(bf16x8*)(dst) = o0;
    *(bf16x8*)(dst + 8) = o1;
}

// ---------------- 256x256x64 8-phase MFMA core (8 waves, 128 KiB dbuf LDS) ----------------
// Wave (wm = wave>>2, wn = wave&3):
//   A m-frags: rows {wm*64+i*16, 128+wm*64+i*16}  (4 in each 128-row half)
//   B n-frags: rows {wn*32+j*16, 128+wn*32+j*16}  (2 in each half)
// Phases per K-tile: P0 = A0xB0, P1 = A0xB1, P2 = A1xB1, P3 = A1xB0.
// Prefetch one half-tile per phase (A0,B0,A1,B1 of tile t+1); counted vmcnt:
//   P0: vmcnt(2)  -> guarantees A1(t),B1(t) landed (A0(t+1) stays in flight)
//   P3: vmcnt(4)  -> guarantees A0(t+1),B0(t+1) landed (A1,B1(t+1) in flight)
// Main loop never drains vmcnt to 0 (tail tile excepted).
__device__ __forceinline__ void stage_half(const bf16* __restrict__ base, int ld,
                                           bf16* lds, int half, int wave, int lr, int ls) {
#pragma unroll
    for (int i = 0; i < 2; i++) {
        int c = half * 16 + wave * 2 + i;   // 8-row chunk index (wave-uniform)
        int r = c * 8 + lr;
        int gj = ls ^ (r & 7);              // pre-swizzled global k-granule
        async16(base + (size_t)r * ld + gj * 8, lds + c * 512);
    }
    FENCE();  // pin gload_lds issue order for counted-vmcnt arithmetic
}

template<int NT>
__device__ __forceinline__ void mm256_core(const bf16* __restrict__ A,
                                           const bf16* __restrict__ B,
                                           int lda, int ldb,
                                           bf16* sA0, bf16* sA1, bf16* sB0, bf16* sB1,
                                           f32x4 (&acc)[8][4]) {
    int lane = threadIdx.x & 63, wave = threadIdx.x >> 6;
    int wm = wave >> 2, wn = wave & 3;
    int lr = lane >> 3, ls = lane & 7;
    int mr = lane & 15, kq = lane >> 4;

    // prologue: stage tile 0 halves in steady-state order (A0,B0,A1,B1)
    stage_half(A, lda, sA0, 0, wave, lr, ls);
    stage_half(B, ldb, sB0, 0, wave, lr, ls);
    stage_half(A, lda, sA0, 1, wave, lr, ls);
    stage_half(B, ldb, sB0, 1, wave, lr, ls);

    f32x4 z = {0.0f, 0.0f, 0.0f, 0.0f};
#pragma unroll
    for (int i = 0; i < 8; i++)
#pragma unroll
        for (int j = 0; j < 4; j++) acc[i][j] = z;

    WAITV(4);          // A0(0),B0(0) landed; A1,B1 still in flight
    BARRIER();

#pragma unroll 1
    for (int t = 0; t < NT; ++t) {
        bf16* Ad = (t & 1) ? sA1 : sA0;
        bf16* Bd = (t & 1) ? sB1 : sB0;
        bf16* An = (t & 1) ? sA0 : sA1;
        bf16* Bn = (t & 1) ? sB0 : sB1;
        const bf16* Ax = A + (size_t)(t + 1) * BK;
        const bf16* Bx = B + (size_t)(t + 1) * BK;
        bool pf = (t + 1 < NT);
        bf16x8 a0[4][2], a1[4][2], b0[2][2], b1[2][2];

        // ---- P0: A-half0 x B-half0 ----
#pragma unroll
        for (int i = 0; i < 4; i++)
#pragma unroll
            for (int ks = 0; ks < 2; ks++)
                a0[i][ks] = *(const bf16x8*)&Ad[sw_elem(wm * 64 + i * 16 + mr, ks * 4 + kq)];
#pragma unroll
        for (int j = 0; j < 2; j++)
#pragma unroll
            for (int ks = 0; ks < 2; ks++)
                b0[j][ks] = *(const bf16x8*)&Bd[sw_elem(wn * 32 + j * 16 + mr, ks * 4 + kq)];
        if (pf) { stage_half(Ax, lda, An, 0, wave, lr, ls); WAITV(2); }
        else    { WAITV(0); }
        BARRIER();
        WAITLGKM0();
        __builtin_amdgcn_s_setprio(1);
#pragma unroll
        for (int ks = 0; ks < 2; ks++)
#pragma unroll
            for (int i = 0; i < 4; i++)
#pragma unroll
                for (int j = 0; j < 2; j++)
                    acc[i][j] = __builtin_amdgcn_mfma_f32_16x16x32_bf16(a0[i][ks], b0[j][ks], acc[i][j], 0, 0, 0);
        __builtin_amdgcn_s_setprio(0);
        BARRIER();

        // ---- P1: A-half0 x B-half1 ----
#pragma unroll
        for (int j = 0; j < 2; j++)
#pragma unroll
            for (int ks = 0; ks < 2; ks++)
                b1[j][ks] = *(const bf16x8*)&Bd[sw_elem(128 + wn * 32 + j * 16 + mr, ks * 4 + kq)];
        if (pf) stage_half(Bx, ldb, Bn, 0, wave, lr, ls);
        BARRIER();
        WAITLGKM0();
        __builtin_amdgcn_s_setprio(1);
#pragma unroll
        for (int ks = 0; ks < 2; ks++)
#pragma unroll
            for (int i = 0; i < 4; i++)
#pragma unroll
                for (int j = 0; j < 2; j++)
                    acc[i][2 + j] = __builtin_amdgcn_mfma_f32_16x16x32_bf16(a0[i][ks], b1[j][ks], acc[i][2 + j], 0, 0, 0);
        __builtin_amdgcn_s_setprio(0);
        BARRIER();

        // ---- P2: A-half1 x B-half1 ----
#pragma unroll
        for (int i = 0; i < 4; i++)
#pragma unroll
            for (int ks = 0; ks < 2; ks++)
                a1[i][ks] = *(const bf16x8*)&Ad[sw_elem(128 + wm * 64 + i * 16 + mr, ks * 4 + kq)];
        if (pf) stage_half(Ax, lda, An, 1, wave, lr, ls);
        BARRIER();
        WAITLGKM0();
        __builtin_amdgcn_s_setprio(1);
#pragma unroll
        for (int ks = 0; ks < 2; ks++)
#pragma unroll
            for (int i = 0; i < 4; i++)
#pragma unroll
                for (int j = 0; j < 2; j++)
                    acc[4 + i][2 + j] = __builtin_amdgcn_mfma_f32_16x16x32_bf16(a1[i][ks], b1[j][ks], acc[4 + i][2 + j], 0, 0, 0);
        __builtin_amdgcn_s_setprio(0);
        BARRIER();

        // ---- P3: A-half1 x B-half0 (b0 still live in regs) ----
        if (pf) { stage_half(Bx, ldb, Bn, 1, wave, lr, ls); WAITV(4); }
        else    { WAITV(0); }
        BARRIER();
        __builtin_amdgcn_s_setprio(1);
#pragma unroll
        for (int ks = 0; ks < 2; ks++)
#pragma unroll
            for (int i = 0; i < 4; i++)
#pragma unroll
                for (int j = 0; j < 2; j++)
                    acc[4 + i][j] = __builtin_amdgcn_mfma_f32_16x16x32_bf16(a1[i][ks], b0[j][ks], acc[4 + i][j], 0, 0, 0);
        __builtin_amdgcn_s_setprio(0);
        BARRIER();
    }
}

// ---------------- GEMM1: ein @ w01t (interleaved w0/w1), fused GEGLU -> hidden bf16 ----------------
// grid: flat 8*43*8 = 2752, block 512. XCD-chunked swizzle: expert e -> XCD e.
__global__ __launch_bounds__(512, 2) void gemm1_k(const bf16* __restrict__ ein,
                                                  const bf16* __restrict__ w01t,
                                                  bf16* __restrict__ hidden) {
    __shared__ __align__(16) bf16 smem[4 * 256 * BK];   // 128 KiB
    int flat = blockIdx.x;
    int chunk = gridDim.x >> 3;                          // 344 (nwg % 8 == 0)
    int swz = (flat & 7) * chunk + (flat >> 3);
    constexpr int NTL = N1 / 256;                        // 43
    int e = swz / (8 * NTL);
    int rem = swz - e * (8 * NTL);
    int rt = rem & 7;                                    // rt-fastest: B-panel dedup per XCD
    int nt = rem >> 3;
    const bf16* A = ein  + ((size_t)e * GC + (size_t)rt * 256) * MD;
    const bf16* B = w01t + ((size_t)e * N1 + (size_t)nt * 256) * MD;
    f32x4 acc[8][4];
    mm256_core<MD / BK>(A, B, MD, MD, smem, smem + 16384, smem + 32768, smem + 49152, acc);

    // epilogue: acc[i][j] = w0 col, acc[i][j+2] = w1 same col; hidden = gelu(h0)*h1
    int lane = threadIdx.x & 63, wave = threadIdx.x >> 6;
    int wm = wave >> 2, wn = wave & 3;
    bf16* Hb = hidden + (size_t)e * GC * HP;
#pragma unroll
    for (int i = 0; i < 8; i++) {
        int rowb = rt * 256 + (i >> 2) * 128 + wm * 64 + (i & 3) * 16 + (lane >> 4) * 4;
#pragma unroll
        for (int j = 0; j < 2; j++) {
            int col = nt * 128 + wn * 32 + j * 16 + (lane & 15);
            bool ok = col < H;
#pragma unroll
            for (int r = 0; r < 4; r++) {
                float v = ok ? gelu_tanh(acc[i][j][r]) * acc[i][j + 2][r] : 0.0f;
                Hb[(size_t)(rowb + r) * HP + col] = (bf16)v;
            }
        }
    }
}

// ---------------- GEMM2: hidden @ wot -> expert_out fp32 ----------------
// grid: flat 8*4*8 = 256 (exactly 1 block/CU), block 512.
__global__ __launch_bounds__(512, 2) void gemm2_k(const bf16* __restrict__ hidden,
                                                  const bf16* __restrict__ wot,
                                                  float* __restrict__ eout) {
    __shared__ __align__(16) bf16 smem[4 * 256 * BK];   // 128 KiB
    int flat = blockIdx.x;
    int chunk = gridDim.x >> 3;                          // 32
    int swz = (flat & 7) * chunk + (flat >> 3);
    int e = swz >> 5;
    int rem = swz & 31;
    int rt = rem & 7;
    int nt = rem >> 3;
    const bf16* A = hidden + ((size_t)e * GC + (size_t)rt * 256) * HP;
    const bf16* B = wot    + ((size_t)e * MD + (size_t)nt * 256) * HP;
    f32x4 acc[8][4];
    mm256_core<HP / BK>(A, B, HP, HP, smem, smem + 16384, smem + 32768, smem + 49152, acc);

    int lane = threadIdx.x & 63, wave = threadIdx.x >> 6;
    int wm = wave >> 2, wn = wave & 3;
    float* Ob = eout + (size_t)e * GC * MD;
#pragma unroll
    for (int i = 0; i < 8; i++) {
        int rowb = rt * 256 + (i >> 2) * 128 + wm * 64 + (i & 3) * 16 + (lane >> 4) * 4;
#pragma unroll
        for (int j = 0; j < 4; j++) {
            int col = nt * 256 + (j >> 1) * 128 + wn * 32 + (j & 1) * 16 + (lane & 15);
#pragma unroll
            for (int r = 0; r < 4; r++)
                Ob[(size_t)(rowb + r) * MD + col] = acc[i][j][r];
        }
    }
}

// ---------------- combine: out[t] = g1*eout[slot1] + g2*eout[slot2] ----------------
__global__ void combine_k(const float* __restrict__ eout, const int* __restrict__ tok1,
                          const int* __restrict__ tok2, const float* __restrict__ g1m,
                          const float* __restrict__ g2m, float* __restrict__ out) {
    int t = blockIdx.x;
    int g = t >> 10;
    int i = threadIdx.x * 4;
    int r1 = tok1[t], r2 = tok2[t];
    float f1 = g1m[t], f2 = g2m[t];
    float4 o = {0, 0, 0, 0};
    if (r1 >= 0) {
        size_t row = (size_t)(((r1 >> 8) * G + g) * CAP + (r1 & 255));
        float4 v = *(const float4*)(eout + row * MD + i);
        o.x += f1 * v.x; o.y += f1 * v.y; o.z += f1 * v.z; o.w += f1 * v.w;
    }
    if (r2 >= 0) {
        size_t row = (size_t)(((r2 >> 8) * G + g) * CAP + (r2 & 255));
        float4 v = *(const float4*)(eout + row * MD + i);
        o.x += f2 * v.x; o.y += f2 * v.y; o.z += f2 * v.z; o.w += f2 * v.w;
    }
    *(float4*)(out + (size_t)t * MD + i) = o;
}

// ---------------- workspace layout ----------------
constexpr size_t SZ_TI = (size_t)T * 4;
constexpr size_t OFF_IDX1 = 0;
constexpr size_t OFF_IDX2 = OFF_IDX1 + SZ_TI;
constexpr size_t OFF_GT1  = OFF_IDX2 + SZ_TI;
constexpr size_t OFF_GT2  = OFF_GT1 + SZ_TI;
constexpr size_t OFF_G1M  = OFF_GT2 + SZ_TI;
constexpr size_t OFF_G2M  = OFF_G1M + SZ_TI;
constexpr size_t OFF_TK1  = OFF_G2M + SZ_TI;
constexpr size_t OFF_TK2  = OFF_TK1 + SZ_TI;
constexpr size_t OFF_SLOT = OFF_TK2 + SZ_TI;
constexpr size_t OFF_FILL = OFF_SLOT + (size_t)E * G * CAP * 4;
constexpr size_t OFF_EIN  = (OFF_FILL + (size_t)E * G * 4 + 255) & ~(size_t)255;
constexpr size_t OFF_W01T = OFF_EIN + (size_t)E * GC * MD * 2;
constexpr size_t OFF_WOT  = OFF_W01T + (size_t)E * N1 * MD * 2;
constexpr size_t OFF_HID  = OFF_WOT + (size_t)E * MD * HP * 2;
constexpr size_t OFF_EOUT = OFF_HID + (size_t)E * GC * HP * 2;
// total ~552 MB (same as previous layout; W01T = old W0T+W1T merged)

extern "C" void kernel_launch(void* const* d_in, const int* in_sizes, int n_in,
                              void* d_out, int out_size, void* d_ws, size_t ws_size,
                              hipStream_t stream) {
    const float* x  = (const float*)d_in[0];
    const float* rw = (const float*)d_in[1];
    const float* w0 = (const float*)d_in[2];
    const float* w1 = (const float*)d_in[3];
    const float* wo = (const float*)d_in[4];
    float* out = (float*)d_out;
    char* ws = (char*)d_ws;

    int*   idx1 = (int*)(ws + OFF_IDX1);
    int*   idx2 = (int*)(ws + OFF_IDX2);
    float* gt1  = (float*)(ws + OFF_GT1);
    float* gt2  = (float*)(ws + OFF_GT2);
    float* g1m  = (float*)(ws + OFF_G1M);
    float* g2m  = (float*)(ws + OFF_G2M);
    int*   tk1  = (int*)(ws + OFF_TK1);
    int*   tk2  = (int*)(ws + OFF_TK2);
    int*   slot = (int*)(ws + OFF_SLOT);
    int*   fill = (int*)(ws + OFF_FILL);
    bf16*  ein  = (bf16*)(ws + OFF_EIN);
    bf16*  w01t = (bf16*)(ws + OFF_W01T);
    bf16*  wot  = (bf16*)(ws + OFF_WOT);
    bf16*  hid  = (bf16*)(ws + OFF_HID);
    float* eout = (float*)(ws + OFF_EOUT);

    router_k<<<T / 4, 256, 0, stream>>>(x, rw, idx1, idx2, gt1, gt2);
    scan_k<<<G, 64, 0, stream>>>(idx1, idx2, gt1, gt2, tk1, tk2, g1m, g2m, slot, fill);
    gather_k<<<E * G * CAP, 256, 0, stream>>>(x, slot, fill, ein);
    // weight pre-pass: fp32 -> bf16, K-contiguous; w0/w1 interleaved at 128-row granularity
    transpose_cast_k<<<dim3(HP / 64, MD / 64, E), 256, 0, stream>>>(w0, w01t, MD, H, MD, N1, 0);
    transpose_cast_k<<<dim3(HP / 64, MD / 64, E), 256, 0, stream>>>(w1, w01t, MD, H, MD, N1, 128);
    transpose_cast_k<<<dim3(MD / 64, HP / 64, E), 256, 0, stream>>>(wo, wot, H, MD, HP, MD, -1);
    gemm1_k<<<dim3((GC / 256) * (N1 / 256) * E), 512, 0, stream>>>(ein, w01t, hid);
    gemm2_k<<<dim3((GC / 256) * (MD / 256) * E), 512, 0, stream>>>(hid, wot, eout);
    combine_k<<<T, 256, 0, stream>>>(eout, tk1, tk2, g1m, g2m, out);
}

// Round 2
// 1122.181 us; speedup vs baseline: 1.1126x; 1.0764x over previous
//
#include <hip/hip_runtime.h>
#include <cstdint>
#include <cstddef>

// ---- problem constants ----
constexpr int G = 8;            // groups
constexpr int S = 1024;         // tokens per group
constexpr int E = 8;            // experts
constexpr int MD = 1024;        // model dim
constexpr int H = 5464;         // ffn dim
constexpr int HP = 5504;        // ffn dim padded to 43*128 (= 86*64)
constexpr int CAP = 256;        // capacity per (group, expert)
constexpr int T = G * S;        // 8192 tokens
constexpr int GC = G * CAP;     // 2048 rows per expert
constexpr int BK = 64;          // K-step of the GEMM tiles

typedef __bf16 bf16;
typedef __bf16 bf16x8 __attribute__((ext_vector_type(8)));
typedef __bf16 bf16x4 __attribute__((ext_vector_type(4)));
typedef float f32x4 __attribute__((ext_vector_type(4)));

__device__ __forceinline__ void async16(const void* g, void* l) {
    // global -> LDS direct DMA, 16B per lane; LDS dst = wave-uniform base + lane*16
    __builtin_amdgcn_global_load_lds((__attribute__((address_space(1))) void*)(g),
                                     (__attribute__((address_space(3))) void*)(l),
                                     16, 0, 0);
}

// gelu(tanh approx) via hw exp: tanh(u) = sign(u) * (1-e^{-2|u|})/(1+e^{-2|u|}).
// e^{-2|u|} in (0,1] -> no overflow, no NaN; underflow -> tanh = +-1 exactly.
__device__ __forceinline__ float gelu_fast(float x) {
    float u = 0.7978845608028654f * (x + 0.044715f * x * x * x);
    float t = __expf(-2.0f * fabsf(u));
    float th = (1.0f - t) * __builtin_amdgcn_rcpf(1.0f + t);  // 1+t in [1,2]
    return 0.5f * x * (1.0f + copysignf(th, u));
}

// swizzled element offset inside a [rows][64 k] bf16 LDS tile.
// granule = 8 bf16 (16B). LDS granule (row*8 + s) holds global k-granule (s ^ (row&7)).
__device__ __forceinline__ int sw_elem(int row, int gi) {
    return (row * 8 + (gi ^ (row & 7))) * 8;
}

#define BARRIER()   __builtin_amdgcn_s_barrier()
#define FENCE()     asm volatile("" ::: "memory")
#define WAITV(n)    asm volatile("s_waitcnt vmcnt(" #n ")" ::: "memory")
#define WAITLGKM0() asm volatile("s_waitcnt lgkmcnt(0)" ::: "memory")

// ---------------- router: logits + softmax + top2 (fp32, exact semantics) ----------------
__global__ void router_k(const float* __restrict__ x, const float* __restrict__ rw,
                         int* __restrict__ idx1, int* __restrict__ idx2,
                         float* __restrict__ gate1, float* __restrict__ gate2) {
    int wave = threadIdx.x >> 6, lane = threadIdx.x & 63;
    int t = blockIdx.x * 4 + wave;
    const float* xr = x + (size_t)t * MD;
    float acc[E];
#pragma unroll
    for (int e = 0; e < E; e++) acc[e] = 0.0f;
    for (int m = lane; m < MD; m += 64) {
        float xv = xr[m];
        const float* w = rw + m * E;
#pragma unroll
        for (int e = 0; e < E; e++) acc[e] += xv * w[e];
    }
#pragma unroll
    for (int off = 32; off > 0; off >>= 1) {
#pragma unroll
        for (int e = 0; e < E; e++) acc[e] += __shfl_xor(acc[e], off, 64);
    }
    if (lane == 0) {
        float mx = acc[0];
#pragma unroll
        for (int e = 1; e < E; e++) mx = fmaxf(mx, acc[e]);
        float raw[E]; float sum = 0.0f;
#pragma unroll
        for (int e = 0; e < E; e++) { raw[e] = expf(acc[e] - mx); sum += raw[e]; }
        float inv = 1.0f / sum;
#pragma unroll
        for (int e = 0; e < E; e++) raw[e] *= inv;
        int i1 = 0; float b1 = raw[0];
#pragma unroll
        for (int e = 1; e < E; e++) if (raw[e] > b1) { b1 = raw[e]; i1 = e; }
        int i2 = 0; float b2 = -1.0f;
#pragma unroll
        for (int e = 0; e < E; e++) {
            float v = (e == i1) ? 0.0f : raw[e];
            if (v > b2) { b2 = v; i2 = e; }
        }
        idx1[t] = i1; idx2[t] = i2; gate1[t] = b1; gate2[t] = b2;
    }
}

// ---------------- capacity scan: one wave per group, ballot prefix ----------------
__global__ void scan_k(const int* __restrict__ idx1, const int* __restrict__ idx2,
                       const float* __restrict__ gate1, const float* __restrict__ gate2,
                       int* __restrict__ tok1, int* __restrict__ tok2,
                       float* __restrict__ g1m, float* __restrict__ g2m,
                       int* __restrict__ slot_src, int* __restrict__ fill) {
    int g = blockIdx.x;
    int lane = threadIdx.x;
    unsigned long long lt = (1ull << lane) - 1ull;
    int cnt1[E], cnt2[E];
#pragma unroll
    for (int e = 0; e < E; e++) { cnt1[e] = 0; cnt2[e] = 0; }
    for (int ch = 0; ch < S / 64; ch++) {
        int s = ch * 64 + lane, t = g * S + s;
        int i1 = idx1[t];
        int p = 0;
#pragma unroll
        for (int e = 0; e < E; e++) {
            unsigned long long m = __ballot(i1 == e);
            if (i1 == e) p = cnt1[e] + (int)__popcll(m & lt);
            cnt1[e] += (int)__popcll(m);
        }
        bool kept = p < CAP;
        tok1[t] = kept ? (i1 * CAP + p) : -1;
        g1m[t] = kept ? gate1[t] : 0.0f;
        if (kept) slot_src[((i1 * G + g) << 8) + p] = s;
    }
    int m1c[E];
#pragma unroll
    for (int e = 0; e < E; e++) m1c[e] = min(cnt1[e], CAP);
    for (int ch = 0; ch < S / 64; ch++) {
        int s = ch * 64 + lane, t = g * S + s;
        int i2 = idx2[t];
        float g2 = gate2[t];
        int p = 0;
#pragma unroll
        for (int e = 0; e < E; e++) {
            unsigned long long m = __ballot(i2 == e);
            if (i2 == e) p = m1c[e] + cnt2[e] + (int)__popcll(m & lt);
            cnt2[e] += (int)__popcll(m);
        }
        bool kept = p < CAP;
        bool nz = (g2 != 0.0f);
        tok2[t] = (kept && nz) ? (i2 * CAP + p) : -1;
        g2m[t] = (kept && nz) ? g2 : 0.0f;
        if (kept) slot_src[((i2 * G + g) << 8) + p] = nz ? s : -1;
    }
    if (lane < E) fill[lane * G + g] = min(m1c[lane] + cnt2[lane], CAP);
}

// ---------------- gather tokens into expert_in (bf16), zero unfilled slots ----------------
__global__ void gather_k(const float* __restrict__ x, const int* __restrict__ slot_src,
                         const int* __restrict__ fill, bf16* __restrict__ ein) {
    int slot = blockIdx.x;                       // (e*G+g)*CAP + c
    int c = slot & 255, g = (slot >> 8) & 7, e = slot >> 11;
    int i = threadIdx.x * 4;
    int src = (c < fill[e * G + g]) ? slot_src[slot] : -1;
    bf16x4 v;
    if (src >= 0) {
        float4 f = *(const float4*)(x + ((size_t)(g * S + src)) * MD + i);
        v[0] = (bf16)f.x; v[1] = (bf16)f.y; v[2] = (bf16)f.z; v[3] = (bf16)f.w;
    } else {
        v[0] = (bf16)0.0f; v[1] = (bf16)0.0f; v[2] = (bf16)0.0f; v[3] = (bf16)0.0f;
    }
    *(bf16x4*)(ein + (size_t)slot * MD + i) = v;
}

// ---------------- fp32 -> bf16 transpose with zero pad ----------------
// in:  (R x Cc) fp32 row-major, batch stride R*Cc
// out: (Cp x Rp) bf16 row-major, batch stride Cp*Rp; out[c][r] = (c<Cc && r<R) ? in[r][c] : 0
__global__ void transpose_cast_k(const float* __restrict__ in, bf16* __restrict__ out,
                                 int R, int Cc, int Rp, int Cp) {
    __shared__ float lds[64][65];
    int c0 = blockIdx.x * 64;
    int r0 = blockIdx.y * 64;
    const float* bin = in + (size_t)blockIdx.z * R * Cc;
    bf16* bout = out + (size_t)blockIdx.z * Cp * Rp;
    int tid = threadIdx.x;
    int lr = tid >> 4;
    int lc = (tid & 15) * 4;
#pragma unroll
    for (int i = 0; i < 4; i++) {
        int r = r0 + lr + i * 16;
        float v0 = 0, v1 = 0, v2 = 0, v3 = 0;
        if (r < R) {
            const float* p = bin + (size_t)r * Cc + c0 + lc;
            if (c0 + lc + 3 < Cc) {
                float4 f = *(const float4*)p;
                v0 = f.x; v1 = f.y; v2 = f.z; v3 = f.w;
            } else {
                if (c0 + lc + 0 < Cc) v0 = p[0];
                if (c0 + lc + 1 < Cc) v1 = p[1];
                if (c0 + lc + 2 < Cc) v2 = p[2];
                if (c0 + lc + 3 < Cc) v3 = p[3];
            }
        }
        lds[lr + i * 16][lc + 0] = v0;
        lds[lr + i * 16][lc + 1] = v1;
        lds[lr + i * 16][lc + 2] = v2;
        lds[lr + i * 16][lc + 3] = v3;
    }
    __syncthreads();
    int orr = tid >> 2;            // out-row offset 0..63
    int oc = (tid & 3) * 16;       // out-col offset 0,16,32,48
    bf16x8 o0, o1;
#pragma unroll
    for (int j = 0; j < 8; j++) o0[j] = (bf16)lds[oc + j][orr];
#pragma unroll
    for (int j = 0; j < 8; j++) o1[j] = (bf16)lds[oc + 8 + j][orr];
    bf16* dst = bout + (size_t)(c0 + orr) * Rp + r0 + oc;
    *(bf16x8*)(dst) = o0;
    *(bf16x8*)(dst + 8) = o1;
}

// ---------------- GEMM1: ein @ {w0t,w1t}, fused GEGLU, write hidden bf16 ----------------
// PROVEN structure (951 TF here): block tile M=128 x N=64 (dual-B), 4 waves, 32KB LDS,
// ~3.6 blocks/CU -> inter-block MFMA overlap. K=1024 (NT=16) is too short for the
// 256^2 8-phase template (m248: 848 TF @ K=1024 grouped) -- do NOT re-port it.
// New vs baseline: flat grid + XCD-chunked swizzle (chunk == one expert per XCD ->
// weight panels fetched once per XCD), exp-based gelu (tanhf was ~60us of VALU).
// grid: flat 16*86*8 = 11008, block 256
__global__ __launch_bounds__(256, 3) void gemm1_k(const bf16* __restrict__ ein,
                                                  const bf16* __restrict__ w0t,
                                                  const bf16* __restrict__ w1t,
                                                  bf16* __restrict__ hidden) {
    __shared__ __align__(16) bf16 As[128 * 64];   // 16 KB
    __shared__ __align__(16) bf16 B0s[64 * 64];   // 8 KB
    __shared__ __align__(16) bf16 B1s[64 * 64];   // 8 KB
    int flat = blockIdx.x;
    int chunk = gridDim.x >> 3;                   // 1376 = 16*86 (one expert)
    int swz = (flat & 7) * chunk + (flat >> 3);   // bijective: 11008 % 8 == 0
    int e = swz / 1376;
    int rem = swz - e * 1376;
    int rt = rem & 15;                            // rt-fastest: B-panel shared by 16 blocks
    int nt = rem >> 4;
    int lane = threadIdx.x & 63, wave = threadIdx.x >> 6;
    int wm = wave & 1, wn = wave >> 1;            // wm: 64-row half; wn: 32-col half
    const bf16* A  = ein + ((size_t)e * GC + rt * 128) * MD;
    const bf16* B0 = w0t + ((size_t)e * HP + nt * 64) * MD;
    const bf16* B1 = w1t + ((size_t)e * HP + nt * 64) * MD;
    f32x4 acc0[4][2], acc1[4][2];                 // 16 x f32x4 = 64 AGPR
    f32x4 z = {0.0f, 0.0f, 0.0f, 0.0f};
#pragma unroll
    for (int i = 0; i < 4; i++)
#pragma unroll
        for (int j = 0; j < 2; j++) { acc0[i][j] = z; acc1[i][j] = z; }
    int lr = lane >> 3, ls = lane & 7;
#pragma unroll 1
    for (int kt = 0; kt < MD / 64; kt++) {
        __syncthreads();
        int k0 = kt * 64;
        // A: 16 chunks of 8 rows (4 per wave)
#pragma unroll
        for (int i = 0; i < 4; i++) {
            int c = i * 4 + wave;
            int r = c * 8 + lr;
            int gj = ls ^ (r & 7);
            async16(A + (size_t)r * MD + k0 + gj * 8, &As[c * 512]);
        }
        // B0/B1: 8 chunks of 8 rows each (2 per wave per matrix)
#pragma unroll
        for (int i = 0; i < 2; i++) {
            int c = i * 4 + wave;
            int r = c * 8 + lr;
            int gj = ls ^ (r & 7);
            size_t go = (size_t)r * MD + k0 + gj * 8;
            async16(B0 + go, &B0s[c * 512]);
            async16(B1 + go, &B1s[c * 512]);
        }
        __syncthreads();
#pragma unroll
        for (int ks = 0; ks < 2; ks++) {
            bf16x8 af[4], b0f[2], b1f[2];
            int gi = ks * 4 + (lane >> 4);
            int mrow = wm * 64 + (lane & 15);
            int nrow = wn * 32 + (lane & 15);
#pragma unroll
            for (int i = 0; i < 4; i++) af[i] = *(const bf16x8*)&As[sw_elem(mrow + i * 16, gi)];
#pragma unroll
            for (int j = 0; j < 2; j++) {
                b0f[j] = *(const bf16x8*)&B0s[sw_elem(nrow + j * 16, gi)];
                b1f[j] = *(const bf16x8*)&B1s[sw_elem(nrow + j * 16, gi)];
            }
#pragma unroll
            for (int i = 0; i < 4; i++)
#pragma unroll
                for (int j = 0; j < 2; j++) {
                    acc0[i][j] = __builtin_amdgcn_mfma_f32_16x16x32_bf16(af[i], b0f[j], acc0[i][j], 0, 0, 0);
                    acc1[i][j] = __builtin_amdgcn_mfma_f32_16x16x32_bf16(af[i], b1f[j], acc1[i][j], 0, 0, 0);
                }
        }
    }
    // epilogue: hidden = gelu(h0) * h1, zero the HP pad columns
    bf16* Hb = hidden + (size_t)e * GC * HP;
    int colb = nt * 64 + wn * 32 + (lane & 15);
    int rowb = rt * 128 + wm * 64 + ((lane >> 4) * 4);
#pragma unroll
    for (int i = 0; i < 4; i++)
#pragma unroll
        for (int j = 0; j < 2; j++) {
            int col = colb + j * 16;
            bool ok = col < H;
#pragma unroll
            for (int r = 0; r < 4; r++) {
                int row = rowb + i * 16 + r;
                float v = ok ? gelu_fast(acc0[i][j][r]) * acc1[i][j][r] : 0.0f;
                Hb[(size_t)row * HP + col] = (bf16)v;
            }
        }
}

// ---------------- 256x256x64 8-phase MFMA core (8 waves, 128 KiB dbuf LDS) ----------------
// Kept for GEMM2 only: K=5504 (NT=86, deep pipeline) + grid=256 (one round, 1 block/CU)
// is the regime where this template wins.
__device__ __forceinline__ void stage_half(const bf16* __restrict__ base, int ld,
                                           bf16* lds, int half, int wave, int lr, int ls) {
#pragma unroll
    for (int i = 0; i < 2; i++) {
        int c = half * 16 + wave * 2 + i;   // 8-row chunk index (wave-uniform)
        int r = c * 8 + lr;
        int gj = ls ^ (r & 7);              // pre-swizzled global k-granule
        async16(base + (size_t)r * ld + gj * 8, lds + c * 512);
    }
    FENCE();  // pin gload_lds issue order for counted-vmcnt arithmetic
}

template<int NT>
__device__ __forceinline__ void mm256_core(const bf16* __restrict__ A,
                                           const bf16* __restrict__ B,
                                           int lda, int ldb,
                                           bf16* sA0, bf16* sA1, bf16* sB0, bf16* sB1,
                                           f32x4 (&acc)[8][4]) {
    int lane = threadIdx.x & 63, wave = threadIdx.x >> 6;
    int wm = wave >> 2, wn = wave & 3;
    int lr = lane >> 3, ls = lane & 7;
    int mr = lane & 15, kq = lane >> 4;

    // prologue: stage tile 0 halves in steady-state order (A0,B0,A1,B1)
    stage_half(A, lda, sA0, 0, wave, lr, ls);
    stage_half(B, ldb, sB0, 0, wave, lr, ls);
    stage_half(A, lda, sA0, 1, wave, lr, ls);
    stage_half(B, ldb, sB0, 1, wave, lr, ls);

    f32x4 z = {0.0f, 0.0f, 0.0f, 0.0f};
#pragma unroll
    for (int i = 0; i < 8; i++)
#pragma unroll
        for (int j = 0; j < 4; j++) acc[i][j] = z;

    WAITV(4);          // A0(0),B0(0) landed; A1,B1 still in flight
    BARRIER();

#pragma unroll 1
    for (int t = 0; t < NT; ++t) {
        bf16* Ad = (t & 1) ? sA1 : sA0;
        bf16* Bd = (t & 1) ? sB1 : sB0;
        bf16* An = (t & 1) ? sA0 : sA1;
        bf16* Bn = (t & 1) ? sB0 : sB1;
        const bf16* Ax = A + (size_t)(t + 1) * BK;
        const bf16* Bx = B + (size_t)(t + 1) * BK;
        bool pf = (t + 1 < NT);
        bf16x8 a0[4][2], a1[4][2], b0[2][2], b1[2][2];

        // ---- P0: A-half0 x B-half0 ----
#pragma unroll
        for (int i = 0; i < 4; i++)
#pragma unroll
            for (int ks = 0; ks < 2; ks++)
                a0[i][ks] = *(const bf16x8*)&Ad[sw_elem(wm * 64 + i * 16 + mr, ks * 4 + kq)];
#pragma unroll
        for (int j = 0; j < 2; j++)
#pragma unroll
            for (int ks = 0; ks < 2; ks++)
                b0[j][ks] = *(const bf16x8*)&Bd[sw_elem(wn * 32 + j * 16 + mr, ks * 4 + kq)];
        if (pf) { stage_half(Ax, lda, An, 0, wave, lr, ls); WAITV(2); }
        else    { WAITV(0); }
        BARRIER();
        WAITLGKM0();
        __builtin_amdgcn_s_setprio(1);
#pragma unroll
        for (int ks = 0; ks < 2; ks++)
#pragma unroll
            for (int i = 0; i < 4; i++)
#pragma unroll
                for (int j = 0; j < 2; j++)
                    acc[i][j] = __builtin_amdgcn_mfma_f32_16x16x32_bf16(a0[i][ks], b0[j][ks], acc[i][j], 0, 0, 0);
        __builtin_amdgcn_s_setprio(0);
        BARRIER();

        // ---- P1: A-half0 x B-half1 ----
#pragma unroll
        for (int j = 0; j < 2; j++)
#pragma unroll
            for (int ks = 0; ks < 2; ks++)
                b1[j][ks] = *(const bf16x8*)&Bd[sw_elem(128 + wn * 32 + j * 16 + mr, ks * 4 + kq)];
        if (pf) stage_half(Bx, ldb, Bn, 0, wave, lr, ls);
        BARRIER();
        WAITLGKM0();
        __builtin_amdgcn_s_setprio(1);
#pragma unroll
        for (int ks = 0; ks < 2; ks++)
#pragma unroll
            for (int i = 0; i < 4; i++)
#pragma unroll
                for (int j = 0; j < 2; j++)
                    acc[i][2 + j] = __builtin_amdgcn_mfma_f32_16x16x32_bf16(a0[i][ks], b1[j][ks], acc[i][2 + j], 0, 0, 0);
        __builtin_amdgcn_s_setprio(0);
        BARRIER();

        // ---- P2: A-half1 x B-half1 ----
#pragma unroll
        for (int i = 0; i < 4; i++)
#pragma unroll
            for (int ks = 0; ks < 2; ks++)
                a1[i][ks] = *(const bf16x8*)&Ad[sw_elem(128 + wm * 64 + i * 16 + mr, ks * 4 + kq)];
        if (pf) stage_half(Ax, lda, An, 1, wave, lr, ls);
        BARRIER();
        WAITLGKM0();
        __builtin_amdgcn_s_setprio(1);
#pragma unroll
        for (int ks = 0; ks < 2; ks++)
#pragma unroll
            for (int i = 0; i < 4; i++)
#pragma unroll
                for (int j = 0; j < 2; j++)
                    acc[4 + i][2 + j] = __builtin_amdgcn_mfma_f32_16x16x32_bf16(a1[i][ks], b1[j][ks], acc[4 + i][2 + j], 0, 0, 0);
        __builtin_amdgcn_s_setprio(0);
        BARRIER();

        // ---- P3: A-half1 x B-half0 (b0 still live in regs) ----
        if (pf) { stage_half(Bx, ldb, Bn, 1, wave, lr, ls); WAITV(4); }
        else    { WAITV(0); }
        BARRIER();
        __builtin_amdgcn_s_setprio(1);
#pragma unroll
        for (int ks = 0; ks < 2; ks++)
#pragma unroll
            for (int i = 0; i < 4; i++)
#pragma unroll
                for (int j = 0; j < 2; j++)
                    acc[4 + i][j] = __builtin_amdgcn_mfma_f32_16x16x32_bf16(a1[i][ks], b0[j][ks], acc[4 + i][j], 0, 0, 0);
        __builtin_amdgcn_s_setprio(0);
        BARRIER();
    }
}

// ---------------- GEMM2: hidden @ wot -> expert_out fp32 ----------------
// grid: flat 8*4*8 = 256 (exactly 1 block/CU), block 512.
__global__ __launch_bounds__(512, 2) void gemm2_k(const bf16* __restrict__ hidden,
                                                  const bf16* __restrict__ wot,
                                                  float* __restrict__ eout) {
    __shared__ __align__(16) bf16 smem[4 * 256 * BK];   // 128 KiB
    int flat = blockIdx.x;
    int chunk = gridDim.x >> 3;                          // 32
    int swz = (flat & 7) * chunk + (flat >> 3);
    int e = swz >> 5;
    int rem = swz & 31;
    int rt = rem & 7;
    int nt = rem >> 3;
    const bf16* A = hidden + ((size_t)e * GC + (size_t)rt * 256) * HP;
    const bf16* B = wot    + ((size_t)e * MD + (size_t)nt * 256) * HP;
    f32x4 acc[8][4];
    mm256_core<HP / BK>(A, B, HP, HP, smem, smem + 16384, smem + 32768, smem + 49152, acc);

    int lane = threadIdx.x & 63, wave = threadIdx.x >> 6;
    int wm = wave >> 2, wn = wave & 3;
    float* Ob = eout + (size_t)e * GC * MD;
#pragma unroll
    for (int i = 0; i < 8; i++) {
        int rowb = rt * 256 + (i >> 2) * 128 + wm * 64 + (i & 3) * 16 + (lane >> 4) * 4;
#pragma unroll
        for (int j = 0; j < 4; j++) {
            int col = nt * 256 + (j >> 1) * 128 + wn * 32 + (j & 1) * 16 + (lane & 15);
#pragma unroll
            for (int r = 0; r < 4; r++)
                Ob[(size_t)(rowb + r) * MD + col] = acc[i][j][r];
        }
    }
}

// ---------------- combine: out[t] = g1*eout[slot1] + g2*eout[slot2] ----------------
__global__ void combine_k(const float* __restrict__ eout, const int* __restrict__ tok1,
                          const int* __restrict__ tok2, const float* __restrict__ g1m,
                          const float* __restrict__ g2m, float* __restrict__ out) {
    int t = blockIdx.x;
    int g = t >> 10;
    int i = threadIdx.x * 4;
    int r1 = tok1[t], r2 = tok2[t];
    float f1 = g1m[t], f2 = g2m[t];
    float4 o = {0, 0, 0, 0};
    if (r1 >= 0) {
        size_t row = (size_t)(((r1 >> 8) * G + g) * CAP + (r1 & 255));
        float4 v = *(const float4*)(eout + row * MD + i);
        o.x += f1 * v.x; o.y += f1 * v.y; o.z += f1 * v.z; o.w += f1 * v.w;
    }
    if (r2 >= 0) {
        size_t row = (size_t)(((r2 >> 8) * G + g) * CAP + (r2 & 255));
        float4 v = *(const float4*)(eout + row * MD + i);
        o.x += f2 * v.x; o.y += f2 * v.y; o.z += f2 * v.z; o.w += f2 * v.w;
    }
    *(float4*)(out + (size_t)t * MD + i) = o;
}

// ---------------- workspace layout ----------------
constexpr size_t SZ_TI = (size_t)T * 4;
constexpr size_t OFF_IDX1 = 0;
constexpr size_t OFF_IDX2 = OFF_IDX1 + SZ_TI;
constexpr size_t OFF_GT1  = OFF_IDX2 + SZ_TI;
constexpr size_t OFF_GT2  = OFF_GT1 + SZ_TI;
constexpr size_t OFF_G1M  = OFF_GT2 + SZ_TI;
constexpr size_t OFF_G2M  = OFF_G1M + SZ_TI;
constexpr size_t OFF_TK1  = OFF_G2M + SZ_TI;
constexpr size_t OFF_TK2  = OFF_TK1 + SZ_TI;
constexpr size_t OFF_SLOT = OFF_TK2 + SZ_TI;
constexpr size_t OFF_FILL = OFF_SLOT + (size_t)E * G * CAP * 4;
constexpr size_t OFF_EIN  = (OFF_FILL + (size_t)E * G * 4 + 255) & ~(size_t)255;
constexpr size_t OFF_W0T  = OFF_EIN + (size_t)E * GC * MD * 2;
constexpr size_t OFF_W1T  = OFF_W0T + (size_t)E * HP * MD * 2;
constexpr size_t OFF_WOT  = OFF_W1T + (size_t)E * HP * MD * 2;
constexpr size_t OFF_HID  = OFF_WOT + (size_t)E * MD * HP * 2;
constexpr size_t OFF_EOUT = OFF_HID + (size_t)E * GC * HP * 2;
// total ~552 MB

extern "C" void kernel_launch(void* const* d_in, const int* in_sizes, int n_in,
                              void* d_out, int out_size, void* d_ws, size_t ws_size,
                              hipStream_t stream) {
    const float* x  = (const float*)d_in[0];
    const float* rw = (const float*)d_in[1];
    const float* w0 = (const float*)d_in[2];
    const float* w1 = (const float*)d_in[3];
    const float* wo = (const float*)d_in[4];
    float* out = (float*)d_out;
    char* ws = (char*)d_ws;

    int*   idx1 = (int*)(ws + OFF_IDX1);
    int*   idx2 = (int*)(ws + OFF_IDX2);
    float* gt1  = (float*)(ws + OFF_GT1);
    float* gt2  = (float*)(ws + OFF_GT2);
    float* g1m  = (float*)(ws + OFF_G1M);
    float* g2m  = (float*)(ws + OFF_G2M);
    int*   tk1  = (int*)(ws + OFF_TK1);
    int*   tk2  = (int*)(ws + OFF_TK2);
    int*   slot = (int*)(ws + OFF_SLOT);
    int*   fill = (int*)(ws + OFF_FILL);
    bf16*  ein  = (bf16*)(ws + OFF_EIN);
    bf16*  w0t  = (bf16*)(ws + OFF_W0T);
    bf16*  w1t  = (bf16*)(ws + OFF_W1T);
    bf16*  wot  = (bf16*)(ws + OFF_WOT);
    bf16*  hid  = (bf16*)(ws + OFF_HID);
    float* eout = (float*)(ws + OFF_EOUT);

    router_k<<<T / 4, 256, 0, stream>>>(x, rw, idx1, idx2, gt1, gt2);
    scan_k<<<G, 64, 0, stream>>>(idx1, idx2, gt1, gt2, tk1, tk2, g1m, g2m, slot, fill);
    gather_k<<<E * G * CAP, 256, 0, stream>>>(x, slot, fill, ein);
    // weight pre-pass: fp32 -> bf16, transposed to K-contiguous, zero-padded
    transpose_cast_k<<<dim3(HP / 64, MD / 64, E), 256, 0, stream>>>(w0, w0t, MD, H, MD, HP);
    transpose_cast_k<<<dim3(HP / 64, MD / 64, E), 256, 0, stream>>>(w1, w1t, MD, H, MD, HP);
    transpose_cast_k<<<dim3(MD / 64, HP / 64, E), 256, 0, stream>>>(wo, wot, H, MD, HP, MD);
    gemm1_k<<<dim3(16 * 86 * 8), 256, 0, stream>>>(ein, w0t, w1t, hid);
    gemm2_k<<<dim3((GC / 256) * (MD / 256) * E), 512, 0, stream>>>(hid, wot, eout);
    combine_k<<<T, 256, 0, stream>>>(eout, tk1, tk2, g1m, g2m, out);
}